// Round 11
// baseline (155.319 us; speedup 1.0000x reference)
//
#include <hip/hip_runtime.h>
#include <hip/hip_bf16.h>
#include <stdint.h>

#define G_    128
#define NP_   1024
#define F_    16
#define K_    16
#define H_    64
#define L_    64
#define OUT_  128

typedef short  short8v  __attribute__((ext_vector_type(8)));
typedef float  f32x16   __attribute__((ext_vector_type(16)));
typedef float  f32x4    __attribute__((ext_vector_type(4)));

__device__ __forceinline__ uint16_t bf_rne(float f) {
    uint32_t u = __float_as_uint(f);
    return (uint16_t)((u + 0x7FFFu + ((u >> 16) & 1u)) >> 16);
}
__device__ __forceinline__ float bf_to_f(uint16_t h) {
    return __uint_as_float((uint32_t)h << 16);
}

// ---------------------------------------------------------------------------
// prep: per row p, write MFMA A-fragments (bf16 hi/lo, both k-octets) and
// sq in MFMA-permuted order sqp[(g*32+s)*32 + hi*16 + r].
// Pure function of x; every output written exactly once. (R8 logic — its
// distance path validated at absmax 0.0039.)
// ---------------------------------------------------------------------------
__global__ __launch_bounds__(256) void prep_kernel(
    const float* __restrict__ x, uint16_t* __restrict__ zh,
    uint16_t* __restrict__ zl, float* __restrict__ sqp)
{
    const int p = blockIdx.x * 256 + threadIdx.x;       // 0..131071
    const float4* xr = (const float4*)(x + (size_t)p * 16);
    float4 c0 = xr[0], c1 = xr[1], c2 = xr[2], c3 = xr[3];
    float fv[16] = {c0.x,c0.y,c0.z,c0.w, c1.x,c1.y,c1.z,c1.w,
                    c2.x,c2.y,c2.z,c2.w, c3.x,c3.y,c3.z,c3.w};
    float sq = 0.f;
#pragma unroll
    for (int e = 0; e < 16; ++e) sq = fmaf(fv[e], fv[e], sq);

    short8v hv0, hv1, lv0, lv1;
#pragma unroll
    for (int e = 0; e < 8; ++e) {
        uint16_t hb = bf_rne(fv[e]);
        hv0[e] = (short)hb;
        lv0[e] = (short)bf_rne(fv[e] - bf_to_f(hb));
    }
#pragma unroll
    for (int e = 0; e < 8; ++e) {
        uint16_t hb = bf_rne(fv[8 + e]);
        hv1[e] = (short)hb;
        lv1[e] = (short)bf_rne(fv[8 + e] - bf_to_f(hb));
    }
    const size_t eb = (size_t)(p >> 5) * 64 + (p & 31);
    *(short8v*)&zh[eb * 8]        = hv0;
    *(short8v*)&zh[(eb + 32) * 8] = hv1;
    *(short8v*)&zl[eb * 8]        = lv0;
    *(short8v*)&zl[(eb + 32) * 8] = lv1;

    // inverse of jmap(r,hi) = (r&3) + 8*(r>>2) + 4*hi
    const int r32 = p & 31;
    const int hi  = (r32 >> 2) & 1;
    const int r   = (r32 & 3) | ((r32 >> 3) << 2);
    sqp[(size_t)((p >> 5) << 5) + (hi << 4) + r] = sq;
}

// ---------------------------------------------------------------------------
// knn: block = 512 thr = 8 waves = 4 query-tiles(32q) x j-halves(2).
// grid = G*8 = 1024 (XCD-swizzled: a group's 8 blocks share b&7 -> one L2).
// Main loop: zero LDS, zero barriers. A-frags + sq from global (L2-resident),
// 3 chained MFMAs (hi/lo exact, sq in C-init), sort-network top-16 update.
// Occupancy: 8192 waves, ~52 VGPR, 8.7KB LDS -> 8 waves/SIMD.
// Merges: lane<->lane+32 shfl (bitonic), j-halves via LDS (bitonic).
// ---------------------------------------------------------------------------
__global__ __launch_bounds__(512, 8) void knn_kernel(
    const float* __restrict__ x, const uint16_t* __restrict__ zh,
    const uint16_t* __restrict__ zl, const float* __restrict__ sqp,
    int* __restrict__ idxw)
{
    __shared__ float mrg[4][32][17];   // 8.7 KB; (col*17)%32 all-distinct

    const int b    = blockIdx.x;
    const int xcd  = b & 7, slot = b >> 3;
    const int g    = xcd + ((slot & 15) << 3);
    const int qoct = slot >> 4;                       // 0..7
    const int tid  = threadIdx.x;
    const int lane = tid & 63;
    const int w    = tid >> 6;
    const int qtile = w & 3, jh = w >> 2;
    const int col  = lane & 31;
    const int hi   = lane >> 5;
    const int qbase = qoct * 128 + qtile * 32;        // within group

    // --- B fragments: queries, -2 folded, hi/lo split ---
    short8v Bh, Bl;
    {
        const float* qsrc = x + ((size_t)g * NP_ + qbase + col) * 16 + hi * 8;
        float4 q0 = ((const float4*)qsrc)[0];
        float4 q1 = ((const float4*)qsrc)[1];
        float qv[8] = {q0.x,q0.y,q0.z,q0.w, q1.x,q1.y,q1.z,q1.w};
#pragma unroll
        for (int e = 0; e < 8; ++e) {
            float m2 = -2.f * qv[e];
            uint16_t hb = bf_rne(m2);
            Bh[e] = (short)hb;
            Bl[e] = (short)bf_rne(m2 - bf_to_f(hb));
        }
    }

    const uint16_t* zhg = zh + (size_t)(g * 32) * 64 * 8;
    const uint16_t* zlg = zl + (size_t)(g * 32) * 64 * 8;
    const float*    sqg = sqp + ((size_t)g << 10) + (hi << 4);
    const uint32_t  hib = (uint32_t)(hi << 2);

    float hp[16];
#pragma unroll
    for (int m = 0; m < 16; ++m) hp[m] = __uint_as_float(0x7F000000u);

    // compare-exchange (ascending): 1 v_min + 1 v_max, full-rate
#define CE(a, i, j) { float t_lo = fminf(a[i], a[j]);                         \
                      float t_hi = fmaxf(a[i], a[j]);                         \
                      a[i] = t_lo; a[j] = t_hi; }
    // bitonic merge of sorted-asc hp with sorted-asc other-list ol:
    // keep 16 smallest, result sorted asc in hp. 16 min + 32 CE.
#define BMERGE(hp, ol)                                                        \
    {                                                                         \
        float c[16];                                                          \
        _Pragma("unroll")                                                     \
        for (int i = 0; i < 16; ++i) c[i] = fminf(hp[i], ol[15 - i]);         \
        CE(c,0,8)  CE(c,1,9)  CE(c,2,10) CE(c,3,11)                           \
        CE(c,4,12) CE(c,5,13) CE(c,6,14) CE(c,7,15)                           \
        CE(c,0,4)  CE(c,1,5)  CE(c,2,6)  CE(c,3,7)                            \
        CE(c,8,12) CE(c,9,13) CE(c,10,14) CE(c,11,15)                         \
        CE(c,0,2)  CE(c,1,3)  CE(c,4,6)  CE(c,5,7)                            \
        CE(c,8,10) CE(c,9,11) CE(c,12,14) CE(c,13,15)                         \
        CE(c,0,1)  CE(c,2,3)  CE(c,4,5)  CE(c,6,7)                            \
        CE(c,8,9)  CE(c,10,11) CE(c,12,13) CE(c,14,15)                        \
        _Pragma("unroll")                                                     \
        for (int i = 0; i < 16; ++i) hp[i] = c[i];                            \
    }

#pragma unroll 2
    for (int si = 0; si < 16; ++si) {
        const int s = (jh << 4) + si;
        short8v Ah = *(const short8v*)&zhg[(size_t)(s * 64 + lane) * 8];
        short8v Al = *(const short8v*)&zlg[(size_t)(s * 64 + lane) * 8];
        const float* sb = sqg + s * 32;
        f32x4 q0 = *(const f32x4*)(sb + 0);
        f32x4 q1 = *(const f32x4*)(sb + 4);
        f32x4 q2 = *(const f32x4*)(sb + 8);
        f32x4 q3 = *(const f32x4*)(sb + 12);

        // C-init carries sq_j: acc = sq_j - 2*dot after the 3 MFMAs
        f32x16 acc = {q0[0],q0[1],q0[2],q0[3], q1[0],q1[1],q1[2],q1[3],
                      q2[0],q2[1],q2[2],q2[3], q3[0],q3[1],q3[2],q3[3]};
        acc = __builtin_amdgcn_mfma_f32_32x32x16_bf16(Ah, Bl, acc, 0, 0, 0); // hl
        acc = __builtin_amdgcn_mfma_f32_32x32x16_bf16(Al, Bh, acc, 0, 0, 0); // lh
        acc = __builtin_amdgcn_mfma_f32_32x32x16_bf16(Ah, Bh, acc, 0, 0, 0); // hh

        // pack index into low 10 mantissa bits: (d & ~1023) | j
        const uint32_t jb = ((uint32_t)s << 5) | hib;
        float kk[16];
#pragma unroll
        for (int r = 0; r < 16; ++r) {
            uint32_t jv = jb | (uint32_t)((r & 3) + 8 * (r >> 2));
            kk[r] = __uint_as_float((__float_as_uint(acc[r]) & 0xFFFFFC00u) | jv);
        }

        // Batcher odd-even mergesort, 16 keys ascending (63 CE)
        CE(kk,0,1)  CE(kk,2,3)  CE(kk,4,5)  CE(kk,6,7)
        CE(kk,8,9)  CE(kk,10,11) CE(kk,12,13) CE(kk,14,15)
        CE(kk,0,2)  CE(kk,1,3)  CE(kk,4,6)  CE(kk,5,7)
        CE(kk,8,10) CE(kk,9,11) CE(kk,12,14) CE(kk,13,15)
        CE(kk,1,2)  CE(kk,5,6)  CE(kk,9,10) CE(kk,13,14)
        CE(kk,0,4)  CE(kk,1,5)  CE(kk,2,6)  CE(kk,3,7)
        CE(kk,8,12) CE(kk,9,13) CE(kk,10,14) CE(kk,11,15)
        CE(kk,2,4)  CE(kk,3,5)  CE(kk,10,12) CE(kk,11,13)
        CE(kk,1,2)  CE(kk,3,4)  CE(kk,5,6)
        CE(kk,9,10) CE(kk,11,12) CE(kk,13,14)
        CE(kk,0,8)  CE(kk,1,9)  CE(kk,2,10) CE(kk,3,11)
        CE(kk,4,12) CE(kk,5,13) CE(kk,6,14) CE(kk,7,15)
        CE(kk,4,8)  CE(kk,5,9)  CE(kk,6,10) CE(kk,7,11)
        CE(kk,2,4)  CE(kk,3,5)  CE(kk,6,8)  CE(kk,7,9)
        CE(kk,10,12) CE(kk,11,13)
        CE(kk,1,2)  CE(kk,3,4)  CE(kk,5,6)  CE(kk,7,8)
        CE(kk,9,10) CE(kk,11,12) CE(kk,13,14)

        BMERGE(hp, kk)
    }

    // --- merge partner half (lane q <-> q+32): both lists sorted asc ---
    {
        float ot[16];
#pragma unroll
        for (int m = 0; m < 16; ++m) ot[m] = __shfl_xor(hp[m], 32);
        BMERGE(hp, ot)
    }

    // --- merge j-halves via LDS: jh1 publishes, jh0 merges + writes ---
    if (jh == 1 && lane < 32) {
#pragma unroll
        for (int m = 0; m < 16; ++m) mrg[qtile][col][m] = hp[m];
    }
    __syncthreads();
    if (jh == 0 && lane < 32) {
        float ot[16];
#pragma unroll
        for (int m = 0; m < 16; ++m) ot[m] = mrg[qtile][col][m];
        BMERGE(hp, ot)

        int* row = idxw + ((size_t)g * NP_ + qbase + col) * K_;
#pragma unroll
        for (int m4 = 0; m4 < 4; ++m4) {
            int4 o;
            o.x = (int)(__float_as_uint(hp[m4 * 4 + 0]) & 1023u);
            o.y = (int)(__float_as_uint(hp[m4 * 4 + 1]) & 1023u);
            o.z = (int)(__float_as_uint(hp[m4 * 4 + 2]) & 1023u);
            o.w = (int)(__float_as_uint(hp[m4 * 4 + 3]) & 1023u);
            *(int4*)(row + m4 * 4) = o;
        }
    }
#undef BMERGE
#undef CE
}

// ---------------------------------------------------------------------------
// v-only: v[p][h] = sum_f x[p][f] * W1[16+f][h]   (R9 verbatim)
// ---------------------------------------------------------------------------
__global__ __launch_bounds__(256) void v_kernel(
    const float* __restrict__ x, const float* __restrict__ W1,
    float* __restrict__ v)
{
    const int lane = threadIdx.x & 63;
    const int wave = threadIdx.x >> 6;

    float wb[16];
#pragma unroll
    for (int f = 0; f < 16; ++f) wb[f] = W1[(16 + f) * 64 + lane];

    const int base = blockIdx.x * 64 + wave * 16;
    for (int n = 0; n < 16; ++n) {
        const int p = base + n;
        const float4* xr = (const float4*)(x + (size_t)p * 16);
        float4 a0 = xr[0], a1 = xr[1], a2 = xr[2], a3 = xr[3];
        float xv[16] = {a0.x,a0.y,a0.z,a0.w, a1.x,a1.y,a1.z,a1.w,
                        a2.x,a2.y,a2.z,a2.w, a3.x,a3.y,a3.z,a3.w};
        float vv = 0.f;
#pragma unroll
        for (int f = 0; f < 16; ++f) vv = fmaf(xv[f], wb[f], vv);
        v[(size_t)p * 64 + lane] = vv;
    }
}

// ---------------------------------------------------------------------------
// gather: per-(block,wave) partials, no atomics   (R9 verbatim)
// ---------------------------------------------------------------------------
__global__ __launch_bounds__(256) void gather_kernel(
    const float* __restrict__ x, const float* __restrict__ W1,
    const float* __restrict__ b1, const float* __restrict__ v,
    const int* __restrict__ idxw, float* __restrict__ P)
{
    const int lane = threadIdx.x & 63;
    const int wave = threadIdx.x >> 6;
    const int b    = blockIdx.x;
    const int xcd  = b & 7, slot = b >> 3;
    const int g    = xcd + ((slot & 15) << 3);
    const int chunk = slot >> 4;                       // 0..7
    const int pbase = g * NP_ + chunk * 128 + wave * 32;

    float wd[16];
#pragma unroll
    for (int f = 0; f < 16; ++f)
        wd[f] = W1[f * 64 + lane] - W1[(16 + f) * 64 + lane];
    const float bias = b1[lane];

    const float* vg = v + ((size_t)g << 16);
    float acc = 0.f;
    for (int n = 0; n < 32; ++n) {
        const int ii = pbase + n;
        const float4* xr = (const float4*)(x + (size_t)ii * 16);
        float4 c0 = xr[0], c1 = xr[1], c2 = xr[2], c3 = xr[3];
        float uu = bias;
        uu = fmaf(c0.x, wd[0],  uu); uu = fmaf(c0.y, wd[1],  uu);
        uu = fmaf(c0.z, wd[2],  uu); uu = fmaf(c0.w, wd[3],  uu);
        uu = fmaf(c1.x, wd[4],  uu); uu = fmaf(c1.y, wd[5],  uu);
        uu = fmaf(c1.z, wd[6],  uu); uu = fmaf(c1.w, wd[7],  uu);
        uu = fmaf(c2.x, wd[8],  uu); uu = fmaf(c2.y, wd[9],  uu);
        uu = fmaf(c2.z, wd[10], uu); uu = fmaf(c2.w, wd[11], uu);
        uu = fmaf(c3.x, wd[12], uu); uu = fmaf(c3.y, wd[13], uu);
        uu = fmaf(c3.z, wd[14], uu); uu = fmaf(c3.w, wd[15], uu);

        const int4* irow = (const int4*)(idxw + (size_t)ii * 16);
#pragma unroll
        for (int q = 0; q < 4; ++q) {
            int4 j4 = irow[q];
            float v0 = vg[((size_t)j4.x << 6) + lane];
            float v1 = vg[((size_t)j4.y << 6) + lane];
            float v2 = vg[((size_t)j4.z << 6) + lane];
            float v3 = vg[((size_t)j4.w << 6) + lane];
            acc += fmaxf(0.f, uu + v0);
            acc += fmaxf(0.f, uu + v1);
            acc += fmaxf(0.f, uu + v2);
            acc += fmaxf(0.f, uu + v3);
        }
    }
    P[(size_t)(((g << 3) + chunk) * 4 + wave) * 64 + lane] = acc;
}

// ---------------------------------------------------------------------------
// head: S[g][h] = sum of 32 partial rows; out = ((S/(NP*K))@W2+b2)@Wf+bf
// (R9 verbatim)
// ---------------------------------------------------------------------------
__global__ __launch_bounds__(128) void head_kernel(
    const float* __restrict__ P, const float* __restrict__ W2,
    const float* __restrict__ b2, const float* __restrict__ Wf,
    const float* __restrict__ bf, float* __restrict__ out)
{
    __shared__ float hbar[64];
    __shared__ float t[64];
    const int g = blockIdx.x;
    const int tid = threadIdx.x;
    if (tid < 64) {
        float s = 0.f;
        const float* pr = P + (size_t)g * 32 * 64 + tid;
#pragma unroll
        for (int i = 0; i < 32; ++i) s += pr[i * 64];
        hbar[tid] = s * (1.f / (1024.f * 16.f));
    }
    __syncthreads();
    if (tid < 64) {
        float a = b2[tid];
        for (int h = 0; h < 64; ++h) a = fmaf(hbar[h], W2[h * 64 + tid], a);
        t[tid] = a;
    }
    __syncthreads();
    float a = bf[tid];
    for (int h = 0; h < 64; ++h) a = fmaf(t[h], Wf[h * 128 + tid], a);
    out[g * 128 + tid] = a;
}

// ---------------------------------------------------------------------------
extern "C" void kernel_launch(void* const* d_in, const int* in_sizes, int n_in,
                              void* d_out, int out_size, void* d_ws, size_t ws_size,
                              hipStream_t stream)
{
    const float* x  = (const float*)d_in[0];
    const float* W1 = (const float*)d_in[2];
    const float* b1 = (const float*)d_in[3];
    const float* W2 = (const float*)d_in[4];
    const float* b2 = (const float*)d_in[5];
    const float* Wf = (const float*)d_in[6];
    const float* bf = (const float*)d_in[7];
    float* out = (float*)d_out;

    char* ws = (char*)d_ws;
    const size_t N  = (size_t)G_ * NP_;                 // 131072
    const size_t MB = 1024 * 1024;
    float*    v    = (float*)ws;                        //  0 .. 32MB
    int*      idxw = (int*)(ws + 32 * MB);              // 32 .. 40MB
    float*    P    = (float*)(ws + 40 * MB);            // 40 .. 41MB
    uint16_t* zh   = (uint16_t*)(ws + 41 * MB);         // 41 .. 45MB
    uint16_t* zl   = (uint16_t*)(ws + 45 * MB);         // 45 .. 49MB
    float*    sqp  = (float*)(ws + 49 * MB);            // 49 .. 49.5MB

    prep_kernel  <<<(int)(N / 256), 256, 0, stream>>>(x, zh, zl, sqp);
    knn_kernel   <<<G_ * 8, 512, 0, stream>>>(x, zh, zl, sqp, idxw);
    v_kernel     <<<2048, 256, 0, stream>>>(x, W1, v);
    gather_kernel<<<G_ * 8, 256, 0, stream>>>(x, W1, b1, v, idxw, P);
    head_kernel  <<<G_, 128, 0, stream>>>(P, W2, b2, Wf, bf, out);
}

// Round 12
// 152.140 us; speedup vs baseline: 1.0209x; 1.0209x over previous
//
#include <hip/hip_runtime.h>
#include <hip/hip_bf16.h>
#include <stdint.h>

#define G_    128
#define NP_   1024
#define F_    16
#define K_    16
#define H_    64
#define L_    64
#define OUT_  128

typedef short  short8v  __attribute__((ext_vector_type(8)));
typedef float  f32x16   __attribute__((ext_vector_type(16)));
typedef float  f32x4    __attribute__((ext_vector_type(4)));

__device__ __forceinline__ uint16_t bf_rne(float f) {
    uint32_t u = __float_as_uint(f);
    return (uint16_t)((u + 0x7FFFu + ((u >> 16) & 1u)) >> 16);
}
__device__ __forceinline__ float bf_to_f(uint16_t h) {
    return __uint_as_float((uint32_t)h << 16);
}

// ---------------------------------------------------------------------------
// prep: per row p, write MFMA A-fragments (bf16 hi/lo, both k-octets) and
// sq in MFMA-permuted order. (R11 verbatim)
// ---------------------------------------------------------------------------
__global__ __launch_bounds__(256) void prep_kernel(
    const float* __restrict__ x, uint16_t* __restrict__ zh,
    uint16_t* __restrict__ zl, float* __restrict__ sqp)
{
    const int p = blockIdx.x * 256 + threadIdx.x;       // 0..131071
    const float4* xr = (const float4*)(x + (size_t)p * 16);
    float4 c0 = xr[0], c1 = xr[1], c2 = xr[2], c3 = xr[3];
    float fv[16] = {c0.x,c0.y,c0.z,c0.w, c1.x,c1.y,c1.z,c1.w,
                    c2.x,c2.y,c2.z,c2.w, c3.x,c3.y,c3.z,c3.w};
    float sq = 0.f;
#pragma unroll
    for (int e = 0; e < 16; ++e) sq = fmaf(fv[e], fv[e], sq);

    short8v hv0, hv1, lv0, lv1;
#pragma unroll
    for (int e = 0; e < 8; ++e) {
        uint16_t hb = bf_rne(fv[e]);
        hv0[e] = (short)hb;
        lv0[e] = (short)bf_rne(fv[e] - bf_to_f(hb));
    }
#pragma unroll
    for (int e = 0; e < 8; ++e) {
        uint16_t hb = bf_rne(fv[8 + e]);
        hv1[e] = (short)hb;
        lv1[e] = (short)bf_rne(fv[8 + e] - bf_to_f(hb));
    }
    const size_t eb = (size_t)(p >> 5) * 64 + (p & 31);
    *(short8v*)&zh[eb * 8]        = hv0;
    *(short8v*)&zh[(eb + 32) * 8] = hv1;
    *(short8v*)&zl[eb * 8]        = lv0;
    *(short8v*)&zl[(eb + 32) * 8] = lv1;

    // inverse of jmap(r,hi) = (r&3) + 8*(r>>2) + 4*hi
    const int r32 = p & 31;
    const int hi  = (r32 >> 2) & 1;
    const int r   = (r32 & 3) | ((r32 >> 3) << 2);
    sqp[(size_t)((p >> 5) << 5) + (hi << 4) + r] = sq;
}

// ---------------------------------------------------------------------------
// knn: R11 structure (global A-frags, no main-loop LDS, j-halved waves),
// register-slimmed: pack in-place into acc, bitonic merge in-place on hp.
// launch_bounds(512,4): let the compiler allocate naturally (R10 regime);
// occupancy follows from actual VGPR use.
// ---------------------------------------------------------------------------
__global__ __launch_bounds__(512, 4) void knn_kernel(
    const float* __restrict__ x, const uint16_t* __restrict__ zh,
    const uint16_t* __restrict__ zl, const float* __restrict__ sqp,
    int* __restrict__ idxw)
{
    __shared__ float mrg[4][32][17];   // 8.7 KB; (col*17)%32 all-distinct

    const int b    = blockIdx.x;
    const int xcd  = b & 7, slot = b >> 3;
    const int g    = xcd + ((slot & 15) << 3);
    const int qoct = slot >> 4;                       // 0..7
    const int tid  = threadIdx.x;
    const int lane = tid & 63;
    const int w    = tid >> 6;
    const int qtile = w & 3, jh = w >> 2;
    const int col  = lane & 31;
    const int hi   = lane >> 5;
    const int qbase = qoct * 128 + qtile * 32;        // within group

    // --- B fragments: queries, -2 folded, hi/lo split ---
    short8v Bh, Bl;
    {
        const float* qsrc = x + ((size_t)g * NP_ + qbase + col) * 16 + hi * 8;
        float4 q0 = ((const float4*)qsrc)[0];
        float4 q1 = ((const float4*)qsrc)[1];
        float qv[8] = {q0.x,q0.y,q0.z,q0.w, q1.x,q1.y,q1.z,q1.w};
#pragma unroll
        for (int e = 0; e < 8; ++e) {
            float m2 = -2.f * qv[e];
            uint16_t hb = bf_rne(m2);
            Bh[e] = (short)hb;
            Bl[e] = (short)bf_rne(m2 - bf_to_f(hb));
        }
    }

    const uint16_t* zhg = zh + (size_t)(g * 32) * 64 * 8;
    const uint16_t* zlg = zl + (size_t)(g * 32) * 64 * 8;
    const float*    sqg = sqp + ((size_t)g << 10) + (hi << 4);
    const uint32_t  hib = (uint32_t)(hi << 2);

    float hp[16];
#pragma unroll
    for (int m = 0; m < 16; ++m) hp[m] = __uint_as_float(0x7F000000u);

    // compare-exchange (ascending): 1 v_min + 1 v_max, full-rate
#define CE(a, i, j) { float t_lo = fminf(a[i], a[j]);                         \
                      float t_hi = fmaxf(a[i], a[j]);                         \
                      a[i] = t_lo; a[j] = t_hi; }
    // in-place merge of sorted-asc hp with sorted-asc ol: keep 16 smallest,
    // sorted asc, in hp. 16 fmin + 32 CE, no temp array.
#define BMERGE_IP(hp, ol)                                                     \
    {                                                                         \
        _Pragma("unroll")                                                     \
        for (int i = 0; i < 16; ++i) hp[i] = fminf(hp[i], ol[15 - i]);        \
        CE(hp,0,8)  CE(hp,1,9)  CE(hp,2,10) CE(hp,3,11)                       \
        CE(hp,4,12) CE(hp,5,13) CE(hp,6,14) CE(hp,7,15)                       \
        CE(hp,0,4)  CE(hp,1,5)  CE(hp,2,6)  CE(hp,3,7)                        \
        CE(hp,8,12) CE(hp,9,13) CE(hp,10,14) CE(hp,11,15)                     \
        CE(hp,0,2)  CE(hp,1,3)  CE(hp,4,6)  CE(hp,5,7)                        \
        CE(hp,8,10) CE(hp,9,11) CE(hp,12,14) CE(hp,13,15)                     \
        CE(hp,0,1)  CE(hp,2,3)  CE(hp,4,5)  CE(hp,6,7)                        \
        CE(hp,8,9)  CE(hp,10,11) CE(hp,12,13) CE(hp,14,15)                    \
    }

#pragma unroll 2
    for (int si = 0; si < 16; ++si) {
        const int s = (jh << 4) + si;
        short8v Ah = *(const short8v*)&zhg[(size_t)(s * 64 + lane) * 8];
        short8v Al = *(const short8v*)&zlg[(size_t)(s * 64 + lane) * 8];
        const float* sb = sqg + s * 32;
        f32x4 q0 = *(const f32x4*)(sb + 0);
        f32x4 q1 = *(const f32x4*)(sb + 4);
        f32x4 q2 = *(const f32x4*)(sb + 8);
        f32x4 q3 = *(const f32x4*)(sb + 12);

        // C-init carries sq_j: acc = sq_j - 2*dot after the 3 MFMAs
        f32x16 acc = {q0[0],q0[1],q0[2],q0[3], q1[0],q1[1],q1[2],q1[3],
                      q2[0],q2[1],q2[2],q2[3], q3[0],q3[1],q3[2],q3[3]};
        acc = __builtin_amdgcn_mfma_f32_32x32x16_bf16(Ah, Bl, acc, 0, 0, 0); // hl
        acc = __builtin_amdgcn_mfma_f32_32x32x16_bf16(Al, Bh, acc, 0, 0, 0); // lh
        acc = __builtin_amdgcn_mfma_f32_32x32x16_bf16(Ah, Bh, acc, 0, 0, 0); // hh

        // pack index into low 10 mantissa bits IN PLACE: (d & ~1023) | j
        const uint32_t jb = ((uint32_t)s << 5) | hib;
#pragma unroll
        for (int r = 0; r < 16; ++r) {
            uint32_t jv = jb | (uint32_t)((r & 3) + 8 * (r >> 2));
            acc[r] = __uint_as_float((__float_as_uint(acc[r]) & 0xFFFFFC00u) | jv);
        }

        // Batcher odd-even mergesort on acc, 16 keys ascending (63 CE)
        CE(acc,0,1)  CE(acc,2,3)  CE(acc,4,5)  CE(acc,6,7)
        CE(acc,8,9)  CE(acc,10,11) CE(acc,12,13) CE(acc,14,15)
        CE(acc,0,2)  CE(acc,1,3)  CE(acc,4,6)  CE(acc,5,7)
        CE(acc,8,10) CE(acc,9,11) CE(acc,12,14) CE(acc,13,15)
        CE(acc,1,2)  CE(acc,5,6)  CE(acc,9,10) CE(acc,13,14)
        CE(acc,0,4)  CE(acc,1,5)  CE(acc,2,6)  CE(acc,3,7)
        CE(acc,8,12) CE(acc,9,13) CE(acc,10,14) CE(acc,11,15)
        CE(acc,2,4)  CE(acc,3,5)  CE(acc,10,12) CE(acc,11,13)
        CE(acc,1,2)  CE(acc,3,4)  CE(acc,5,6)
        CE(acc,9,10) CE(acc,11,12) CE(acc,13,14)
        CE(acc,0,8)  CE(acc,1,9)  CE(acc,2,10) CE(acc,3,11)
        CE(acc,4,12) CE(acc,5,13) CE(acc,6,14) CE(acc,7,15)
        CE(acc,4,8)  CE(acc,5,9)  CE(acc,6,10) CE(acc,7,11)
        CE(acc,2,4)  CE(acc,3,5)  CE(acc,6,8)  CE(acc,7,9)
        CE(acc,10,12) CE(acc,11,13)
        CE(acc,1,2)  CE(acc,3,4)  CE(acc,5,6)  CE(acc,7,8)
        CE(acc,9,10) CE(acc,11,12) CE(acc,13,14)

        BMERGE_IP(hp, acc)
    }

    // --- merge partner half (lane q <-> q+32): both lists sorted asc ---
    {
        float ot[16];
#pragma unroll
        for (int m = 0; m < 16; ++m) ot[m] = __shfl_xor(hp[m], 32);
        BMERGE_IP(hp, ot)
    }

    // --- merge j-halves via LDS: jh1 publishes, jh0 merges + writes ---
    if (jh == 1 && lane < 32) {
#pragma unroll
        for (int m = 0; m < 16; ++m) mrg[qtile][col][m] = hp[m];
    }
    __syncthreads();
    if (jh == 0 && lane < 32) {
        float ot[16];
#pragma unroll
        for (int m = 0; m < 16; ++m) ot[m] = mrg[qtile][col][m];
        BMERGE_IP(hp, ot)

        int* row = idxw + ((size_t)g * NP_ + qbase + col) * K_;
#pragma unroll
        for (int m4 = 0; m4 < 4; ++m4) {
            int4 o;
            o.x = (int)(__float_as_uint(hp[m4 * 4 + 0]) & 1023u);
            o.y = (int)(__float_as_uint(hp[m4 * 4 + 1]) & 1023u);
            o.z = (int)(__float_as_uint(hp[m4 * 4 + 2]) & 1023u);
            o.w = (int)(__float_as_uint(hp[m4 * 4 + 3]) & 1023u);
            *(int4*)(row + m4 * 4) = o;
        }
    }
#undef BMERGE_IP
#undef CE
}

// ---------------------------------------------------------------------------
// v-only: v[p][h] = sum_f x[p][f] * W1[16+f][h]   (R11 verbatim)
// ---------------------------------------------------------------------------
__global__ __launch_bounds__(256) void v_kernel(
    const float* __restrict__ x, const float* __restrict__ W1,
    float* __restrict__ v)
{
    const int lane = threadIdx.x & 63;
    const int wave = threadIdx.x >> 6;

    float wb[16];
#pragma unroll
    for (int f = 0; f < 16; ++f) wb[f] = W1[(16 + f) * 64 + lane];

    const int base = blockIdx.x * 64 + wave * 16;
    for (int n = 0; n < 16; ++n) {
        const int p = base + n;
        const float4* xr = (const float4*)(x + (size_t)p * 16);
        float4 a0 = xr[0], a1 = xr[1], a2 = xr[2], a3 = xr[3];
        float xv[16] = {a0.x,a0.y,a0.z,a0.w, a1.x,a1.y,a1.z,a1.w,
                        a2.x,a2.y,a2.z,a2.w, a3.x,a3.y,a3.z,a3.w};
        float vv = 0.f;
#pragma unroll
        for (int f = 0; f < 16; ++f) vv = fmaf(xv[f], wb[f], vv);
        v[(size_t)p * 64 + lane] = vv;
    }
}

// ---------------------------------------------------------------------------
// gather: per-(block,wave) partials, no atomics   (R11 verbatim)
// ---------------------------------------------------------------------------
__global__ __launch_bounds__(256) void gather_kernel(
    const float* __restrict__ x, const float* __restrict__ W1,
    const float* __restrict__ b1, const float* __restrict__ v,
    const int* __restrict__ idxw, float* __restrict__ P)
{
    const int lane = threadIdx.x & 63;
    const int wave = threadIdx.x >> 6;
    const int b    = blockIdx.x;
    const int xcd  = b & 7, slot = b >> 3;
    const int g    = xcd + ((slot & 15) << 3);
    const int chunk = slot >> 4;                       // 0..7
    const int pbase = g * NP_ + chunk * 128 + wave * 32;

    float wd[16];
#pragma unroll
    for (int f = 0; f < 16; ++f)
        wd[f] = W1[f * 64 + lane] - W1[(16 + f) * 64 + lane];
    const float bias = b1[lane];

    const float* vg = v + ((size_t)g << 16);
    float acc = 0.f;
    for (int n = 0; n < 32; ++n) {
        const int ii = pbase + n;
        const float4* xr = (const float4*)(x + (size_t)ii * 16);
        float4 c0 = xr[0], c1 = xr[1], c2 = xr[2], c3 = xr[3];
        float uu = bias;
        uu = fmaf(c0.x, wd[0],  uu); uu = fmaf(c0.y, wd[1],  uu);
        uu = fmaf(c0.z, wd[2],  uu); uu = fmaf(c0.w, wd[3],  uu);
        uu = fmaf(c1.x, wd[4],  uu); uu = fmaf(c1.y, wd[5],  uu);
        uu = fmaf(c1.z, wd[6],  uu); uu = fmaf(c1.w, wd[7],  uu);
        uu = fmaf(c2.x, wd[8],  uu); uu = fmaf(c2.y, wd[9],  uu);
        uu = fmaf(c2.z, wd[10], uu); uu = fmaf(c2.w, wd[11], uu);
        uu = fmaf(c3.x, wd[12], uu); uu = fmaf(c3.y, wd[13], uu);
        uu = fmaf(c3.z, wd[14], uu); uu = fmaf(c3.w, wd[15], uu);

        const int4* irow = (const int4*)(idxw + (size_t)ii * 16);
#pragma unroll
        for (int q = 0; q < 4; ++q) {
            int4 j4 = irow[q];
            float v0 = vg[((size_t)j4.x << 6) + lane];
            float v1 = vg[((size_t)j4.y << 6) + lane];
            float v2 = vg[((size_t)j4.z << 6) + lane];
            float v3 = vg[((size_t)j4.w << 6) + lane];
            acc += fmaxf(0.f, uu + v0);
            acc += fmaxf(0.f, uu + v1);
            acc += fmaxf(0.f, uu + v2);
            acc += fmaxf(0.f, uu + v3);
        }
    }
    P[(size_t)(((g << 3) + chunk) * 4 + wave) * 64 + lane] = acc;
}

// ---------------------------------------------------------------------------
// head: S[g][h] = sum of 32 partial rows; out = ((S/(NP*K))@W2+b2)@Wf+bf
// (R11 verbatim)
// ---------------------------------------------------------------------------
__global__ __launch_bounds__(128) void head_kernel(
    const float* __restrict__ P, const float* __restrict__ W2,
    const float* __restrict__ b2, const float* __restrict__ Wf,
    const float* __restrict__ bf, float* __restrict__ out)
{
    __shared__ float hbar[64];
    __shared__ float t[64];
    const int g = blockIdx.x;
    const int tid = threadIdx.x;
    if (tid < 64) {
        float s = 0.f;
        const float* pr = P + (size_t)g * 32 * 64 + tid;
#pragma unroll
        for (int i = 0; i < 32; ++i) s += pr[i * 64];
        hbar[tid] = s * (1.f / (1024.f * 16.f));
    }
    __syncthreads();
    if (tid < 64) {
        float a = b2[tid];
        for (int h = 0; h < 64; ++h) a = fmaf(hbar[h], W2[h * 64 + tid], a);
        t[tid] = a;
    }
    __syncthreads();
    float a = bf[tid];
    for (int h = 0; h < 64; ++h) a = fmaf(t[h], Wf[h * 128 + tid], a);
    out[g * 128 + tid] = a;
}

// ---------------------------------------------------------------------------
extern "C" void kernel_launch(void* const* d_in, const int* in_sizes, int n_in,
                              void* d_out, int out_size, void* d_ws, size_t ws_size,
                              hipStream_t stream)
{
    const float* x  = (const float*)d_in[0];
    const float* W1 = (const float*)d_in[2];
    const float* b1 = (const float*)d_in[3];
    const float* W2 = (const float*)d_in[4];
    const float* b2 = (const float*)d_in[5];
    const float* Wf = (const float*)d_in[6];
    const float* bf = (const float*)d_in[7];
    float* out = (float*)d_out;

    char* ws = (char*)d_ws;
    const size_t N  = (size_t)G_ * NP_;                 // 131072
    const size_t MB = 1024 * 1024;
    float*    v    = (float*)ws;                        //  0 .. 32MB
    int*      idxw = (int*)(ws + 32 * MB);              // 32 .. 40MB
    float*    P    = (float*)(ws + 40 * MB);            // 40 .. 41MB
    uint16_t* zh   = (uint16_t*)(ws + 41 * MB);         // 41 .. 45MB
    uint16_t* zl   = (uint16_t*)(ws + 45 * MB);         // 45 .. 49MB
    float*    sqp  = (float*)(ws + 49 * MB);            // 49 .. 49.5MB

    prep_kernel  <<<(int)(N / 256), 256, 0, stream>>>(x, zh, zl, sqp);
    knn_kernel   <<<G_ * 8, 512, 0, stream>>>(x, zh, zl, sqp, idxw);
    v_kernel     <<<2048, 256, 0, stream>>>(x, W1, v);
    gather_kernel<<<G_ * 8, 256, 0, stream>>>(x, W1, b1, v, idxw, P);
    head_kernel  <<<G_, 128, 0, stream>>>(P, W2, b2, Wf, bf, out);
}

// Round 13
// 151.457 us; speedup vs baseline: 1.0255x; 1.0045x over previous
//
#include <hip/hip_runtime.h>
#include <hip/hip_bf16.h>
#include <stdint.h>

#define G_    128
#define NP_   1024
#define F_    16
#define K_    16
#define H_    64
#define L_    64
#define OUT_  128

typedef short  short8v  __attribute__((ext_vector_type(8)));
typedef float  f32x16   __attribute__((ext_vector_type(16)));
typedef float  f32x4    __attribute__((ext_vector_type(4)));

__device__ __forceinline__ uint16_t bf_rne(float f) {
    uint32_t u = __float_as_uint(f);
    return (uint16_t)((u + 0x7FFFu + ((u >> 16) & 1u)) >> 16);
}
__device__ __forceinline__ float bf_to_f(uint16_t h) {
    return __uint_as_float((uint32_t)h << 16);
}

// ---------------------------------------------------------------------------
// prep: per row p, write MFMA A-fragments (bf16 hi/lo, both k-octets) and
// sq in MFMA-permuted order. (R11/R12 verbatim)
// ---------------------------------------------------------------------------
__global__ __launch_bounds__(256) void prep_kernel(
    const float* __restrict__ x, uint16_t* __restrict__ zh,
    uint16_t* __restrict__ zl, float* __restrict__ sqp)
{
    const int p = blockIdx.x * 256 + threadIdx.x;       // 0..131071
    const float4* xr = (const float4*)(x + (size_t)p * 16);
    float4 c0 = xr[0], c1 = xr[1], c2 = xr[2], c3 = xr[3];
    float fv[16] = {c0.x,c0.y,c0.z,c0.w, c1.x,c1.y,c1.z,c1.w,
                    c2.x,c2.y,c2.z,c2.w, c3.x,c3.y,c3.z,c3.w};
    float sq = 0.f;
#pragma unroll
    for (int e = 0; e < 16; ++e) sq = fmaf(fv[e], fv[e], sq);

    short8v hv0, hv1, lv0, lv1;
#pragma unroll
    for (int e = 0; e < 8; ++e) {
        uint16_t hb = bf_rne(fv[e]);
        hv0[e] = (short)hb;
        lv0[e] = (short)bf_rne(fv[e] - bf_to_f(hb));
    }
#pragma unroll
    for (int e = 0; e < 8; ++e) {
        uint16_t hb = bf_rne(fv[8 + e]);
        hv1[e] = (short)hb;
        lv1[e] = (short)bf_rne(fv[8 + e] - bf_to_f(hb));
    }
    const size_t eb = (size_t)(p >> 5) * 64 + (p & 31);
    *(short8v*)&zh[eb * 8]        = hv0;
    *(short8v*)&zh[(eb + 32) * 8] = hv1;
    *(short8v*)&zl[eb * 8]        = lv0;
    *(short8v*)&zl[(eb + 32) * 8] = lv1;

    // inverse of jmap(r,hi) = (r&3) + 8*(r>>2) + 4*hi
    const int r32 = p & 31;
    const int hi  = (r32 >> 2) & 1;
    const int r   = (r32 & 3) | ((r32 >> 3) << 2);
    sqp[(size_t)((p >> 5) << 5) + (hi << 4) + r] = sq;
}

// ---------------------------------------------------------------------------
// knn: R12 structure (global A-frags, no main-loop LDS, j-halved waves).
// Codegen fix: sort network operates on a SEPARATE float kk[16] (ArchVGPR),
// never on the MFMA accumulator (AGPR class). AGPR traffic = 16 read +
// 16 write per slab only. launch_bounds(512,4): cap 128, R10-proven regime.
// ---------------------------------------------------------------------------
__global__ __launch_bounds__(512, 4) void knn_kernel(
    const float* __restrict__ x, const uint16_t* __restrict__ zh,
    const uint16_t* __restrict__ zl, const float* __restrict__ sqp,
    int* __restrict__ idxw)
{
    __shared__ float mrg[4][32][17];   // 8.7 KB; (col*17)%32 all-distinct

    const int b    = blockIdx.x;
    const int xcd  = b & 7, slot = b >> 3;
    const int g    = xcd + ((slot & 15) << 3);
    const int qoct = slot >> 4;                       // 0..7
    const int tid  = threadIdx.x;
    const int lane = tid & 63;
    const int w    = tid >> 6;
    const int qtile = w & 3, jh = w >> 2;
    const int col  = lane & 31;
    const int hi   = lane >> 5;
    const int qbase = qoct * 128 + qtile * 32;        // within group

    // --- B fragments: queries, -2 folded, hi/lo split ---
    short8v Bh, Bl;
    {
        const float* qsrc = x + ((size_t)g * NP_ + qbase + col) * 16 + hi * 8;
        float4 q0 = ((const float4*)qsrc)[0];
        float4 q1 = ((const float4*)qsrc)[1];
        float qv[8] = {q0.x,q0.y,q0.z,q0.w, q1.x,q1.y,q1.z,q1.w};
#pragma unroll
        for (int e = 0; e < 8; ++e) {
            float m2 = -2.f * qv[e];
            uint16_t hb = bf_rne(m2);
            Bh[e] = (short)hb;
            Bl[e] = (short)bf_rne(m2 - bf_to_f(hb));
        }
    }

    const uint16_t* zhg = zh + (size_t)(g * 32) * 64 * 8;
    const uint16_t* zlg = zl + (size_t)(g * 32) * 64 * 8;
    const float*    sqg = sqp + ((size_t)g << 10) + (hi << 4);
    const uint32_t  hib = (uint32_t)(hi << 2);

    float hp[16];
#pragma unroll
    for (int m = 0; m < 16; ++m) hp[m] = __uint_as_float(0x7F000000u);

    // compare-exchange (ascending): 1 v_min + 1 v_max, full-rate
#define CE(a, i, j) { float t_lo = fminf(a[i], a[j]);                         \
                      float t_hi = fmaxf(a[i], a[j]);                         \
                      a[i] = t_lo; a[j] = t_hi; }
    // in-place merge of sorted-asc hp with sorted-asc ol: keep 16 smallest,
    // sorted asc, in hp. 16 fmin + 32 CE.
#define BMERGE_IP(hp, ol)                                                     \
    {                                                                         \
        _Pragma("unroll")                                                     \
        for (int i = 0; i < 16; ++i) hp[i] = fminf(hp[i], ol[15 - i]);        \
        CE(hp,0,8)  CE(hp,1,9)  CE(hp,2,10) CE(hp,3,11)                       \
        CE(hp,4,12) CE(hp,5,13) CE(hp,6,14) CE(hp,7,15)                       \
        CE(hp,0,4)  CE(hp,1,5)  CE(hp,2,6)  CE(hp,3,7)                        \
        CE(hp,8,12) CE(hp,9,13) CE(hp,10,14) CE(hp,11,15)                     \
        CE(hp,0,2)  CE(hp,1,3)  CE(hp,4,6)  CE(hp,5,7)                        \
        CE(hp,8,10) CE(hp,9,11) CE(hp,12,14) CE(hp,13,15)                     \
        CE(hp,0,1)  CE(hp,2,3)  CE(hp,4,5)  CE(hp,6,7)                        \
        CE(hp,8,9)  CE(hp,10,11) CE(hp,12,13) CE(hp,14,15)                    \
    }

#pragma unroll 2
    for (int si = 0; si < 16; ++si) {
        const int s = (jh << 4) + si;
        short8v Ah = *(const short8v*)&zhg[(size_t)(s * 64 + lane) * 8];
        short8v Al = *(const short8v*)&zlg[(size_t)(s * 64 + lane) * 8];
        const float* sb = sqg + s * 32;
        f32x4 q0 = *(const f32x4*)(sb + 0);
        f32x4 q1 = *(const f32x4*)(sb + 4);
        f32x4 q2 = *(const f32x4*)(sb + 8);
        f32x4 q3 = *(const f32x4*)(sb + 12);

        // C-init carries sq_j: acc = sq_j - 2*dot after the 3 MFMAs
        f32x16 acc = {q0[0],q0[1],q0[2],q0[3], q1[0],q1[1],q1[2],q1[3],
                      q2[0],q2[1],q2[2],q2[3], q3[0],q3[1],q3[2],q3[3]};
        acc = __builtin_amdgcn_mfma_f32_32x32x16_bf16(Ah, Bl, acc, 0, 0, 0); // hl
        acc = __builtin_amdgcn_mfma_f32_32x32x16_bf16(Al, Bh, acc, 0, 0, 0); // lh
        acc = __builtin_amdgcn_mfma_f32_32x32x16_bf16(Ah, Bh, acc, 0, 0, 0); // hh

        // pack into SEPARATE VGPR array kk (one accvgpr_read per element);
        // index in low 10 mantissa bits: (d & ~1023) | j
        const uint32_t jb = ((uint32_t)s << 5) | hib;
        float kk[16];
#pragma unroll
        for (int r = 0; r < 16; ++r) {
            uint32_t jv = jb | (uint32_t)((r & 3) + 8 * (r >> 2));
            kk[r] = __uint_as_float((__float_as_uint(acc[r]) & 0xFFFFFC00u) | jv);
        }

        // Batcher odd-even mergesort on kk, 16 keys ascending (63 CE)
        CE(kk,0,1)  CE(kk,2,3)  CE(kk,4,5)  CE(kk,6,7)
        CE(kk,8,9)  CE(kk,10,11) CE(kk,12,13) CE(kk,14,15)
        CE(kk,0,2)  CE(kk,1,3)  CE(kk,4,6)  CE(kk,5,7)
        CE(kk,8,10) CE(kk,9,11) CE(kk,12,14) CE(kk,13,15)
        CE(kk,1,2)  CE(kk,5,6)  CE(kk,9,10) CE(kk,13,14)
        CE(kk,0,4)  CE(kk,1,5)  CE(kk,2,6)  CE(kk,3,7)
        CE(kk,8,12) CE(kk,9,13) CE(kk,10,14) CE(kk,11,15)
        CE(kk,2,4)  CE(kk,3,5)  CE(kk,10,12) CE(kk,11,13)
        CE(kk,1,2)  CE(kk,3,4)  CE(kk,5,6)
        CE(kk,9,10) CE(kk,11,12) CE(kk,13,14)
        CE(kk,0,8)  CE(kk,1,9)  CE(kk,2,10) CE(kk,3,11)
        CE(kk,4,12) CE(kk,5,13) CE(kk,6,14) CE(kk,7,15)
        CE(kk,4,8)  CE(kk,5,9)  CE(kk,6,10) CE(kk,7,11)
        CE(kk,2,4)  CE(kk,3,5)  CE(kk,6,8)  CE(kk,7,9)
        CE(kk,10,12) CE(kk,11,13)
        CE(kk,1,2)  CE(kk,3,4)  CE(kk,5,6)  CE(kk,7,8)
        CE(kk,9,10) CE(kk,11,12) CE(kk,13,14)

        BMERGE_IP(hp, kk)
    }

    // --- merge partner half (lane q <-> q+32): both lists sorted asc ---
    {
        float ot[16];
#pragma unroll
        for (int m = 0; m < 16; ++m) ot[m] = __shfl_xor(hp[m], 32);
        BMERGE_IP(hp, ot)
    }

    // --- merge j-halves via LDS: jh1 publishes, jh0 merges + writes ---
    if (jh == 1 && lane < 32) {
#pragma unroll
        for (int m = 0; m < 16; ++m) mrg[qtile][col][m] = hp[m];
    }
    __syncthreads();
    if (jh == 0 && lane < 32) {
        float ot[16];
#pragma unroll
        for (int m = 0; m < 16; ++m) ot[m] = mrg[qtile][col][m];
        BMERGE_IP(hp, ot)

        int* row = idxw + ((size_t)g * NP_ + qbase + col) * K_;
#pragma unroll
        for (int m4 = 0; m4 < 4; ++m4) {
            int4 o;
            o.x = (int)(__float_as_uint(hp[m4 * 4 + 0]) & 1023u);
            o.y = (int)(__float_as_uint(hp[m4 * 4 + 1]) & 1023u);
            o.z = (int)(__float_as_uint(hp[m4 * 4 + 2]) & 1023u);
            o.w = (int)(__float_as_uint(hp[m4 * 4 + 3]) & 1023u);
            *(int4*)(row + m4 * 4) = o;
        }
    }
#undef BMERGE_IP
#undef CE
}

// ---------------------------------------------------------------------------
// v-only: v[p][h] = sum_f x[p][f] * W1[16+f][h]   (R12 verbatim)
// ---------------------------------------------------------------------------
__global__ __launch_bounds__(256) void v_kernel(
    const float* __restrict__ x, const float* __restrict__ W1,
    float* __restrict__ v)
{
    const int lane = threadIdx.x & 63;
    const int wave = threadIdx.x >> 6;

    float wb[16];
#pragma unroll
    for (int f = 0; f < 16; ++f) wb[f] = W1[(16 + f) * 64 + lane];

    const int base = blockIdx.x * 64 + wave * 16;
    for (int n = 0; n < 16; ++n) {
        const int p = base + n;
        const float4* xr = (const float4*)(x + (size_t)p * 16);
        float4 a0 = xr[0], a1 = xr[1], a2 = xr[2], a3 = xr[3];
        float xv[16] = {a0.x,a0.y,a0.z,a0.w, a1.x,a1.y,a1.z,a1.w,
                        a2.x,a2.y,a2.z,a2.w, a3.x,a3.y,a3.z,a3.w};
        float vv = 0.f;
#pragma unroll
        for (int f = 0; f < 16; ++f) vv = fmaf(xv[f], wb[f], vv);
        v[(size_t)p * 64 + lane] = vv;
    }
}

// ---------------------------------------------------------------------------
// gather: per-(block,wave) partials, no atomics   (R12 verbatim)
// ---------------------------------------------------------------------------
__global__ __launch_bounds__(256) void gather_kernel(
    const float* __restrict__ x, const float* __restrict__ W1,
    const float* __restrict__ b1, const float* __restrict__ v,
    const int* __restrict__ idxw, float* __restrict__ P)
{
    const int lane = threadIdx.x & 63;
    const int wave = threadIdx.x >> 6;
    const int b    = blockIdx.x;
    const int xcd  = b & 7, slot = b >> 3;
    const int g    = xcd + ((slot & 15) << 3);
    const int chunk = slot >> 4;                       // 0..7
    const int pbase = g * NP_ + chunk * 128 + wave * 32;

    float wd[16];
#pragma unroll
    for (int f = 0; f < 16; ++f)
        wd[f] = W1[f * 64 + lane] - W1[(16 + f) * 64 + lane];
    const float bias = b1[lane];

    const float* vg = v + ((size_t)g << 16);
    float acc = 0.f;
    for (int n = 0; n < 32; ++n) {
        const int ii = pbase + n;
        const float4* xr = (const float4*)(x + (size_t)ii * 16);
        float4 c0 = xr[0], c1 = xr[1], c2 = xr[2], c3 = xr[3];
        float uu = bias;
        uu = fmaf(c0.x, wd[0],  uu); uu = fmaf(c0.y, wd[1],  uu);
        uu = fmaf(c0.z, wd[2],  uu); uu = fmaf(c0.w, wd[3],  uu);
        uu = fmaf(c1.x, wd[4],  uu); uu = fmaf(c1.y, wd[5],  uu);
        uu = fmaf(c1.z, wd[6],  uu); uu = fmaf(c1.w, wd[7],  uu);
        uu = fmaf(c2.x, wd[8],  uu); uu = fmaf(c2.y, wd[9],  uu);
        uu = fmaf(c2.z, wd[10], uu); uu = fmaf(c2.w, wd[11], uu);
        uu = fmaf(c3.x, wd[12], uu); uu = fmaf(c3.y, wd[13], uu);
        uu = fmaf(c3.z, wd[14], uu); uu = fmaf(c3.w, wd[15], uu);

        const int4* irow = (const int4*)(idxw + (size_t)ii * 16);
#pragma unroll
        for (int q = 0; q < 4; ++q) {
            int4 j4 = irow[q];
            float v0 = vg[((size_t)j4.x << 6) + lane];
            float v1 = vg[((size_t)j4.y << 6) + lane];
            float v2 = vg[((size_t)j4.z << 6) + lane];
            float v3 = vg[((size_t)j4.w << 6) + lane];
            acc += fmaxf(0.f, uu + v0);
            acc += fmaxf(0.f, uu + v1);
            acc += fmaxf(0.f, uu + v2);
            acc += fmaxf(0.f, uu + v3);
        }
    }
    P[(size_t)(((g << 3) + chunk) * 4 + wave) * 64 + lane] = acc;
}

// ---------------------------------------------------------------------------
// head: S[g][h] = sum of 32 partial rows; out = ((S/(NP*K))@W2+b2)@Wf+bf
// (R12 verbatim)
// ---------------------------------------------------------------------------
__global__ __launch_bounds__(128) void head_kernel(
    const float* __restrict__ P, const float* __restrict__ W2,
    const float* __restrict__ b2, const float* __restrict__ Wf,
    const float* __restrict__ bf, float* __restrict__ out)
{
    __shared__ float hbar[64];
    __shared__ float t[64];
    const int g = blockIdx.x;
    const int tid = threadIdx.x;
    if (tid < 64) {
        float s = 0.f;
        const float* pr = P + (size_t)g * 32 * 64 + tid;
#pragma unroll
        for (int i = 0; i < 32; ++i) s += pr[i * 64];
        hbar[tid] = s * (1.f / (1024.f * 16.f));
    }
    __syncthreads();
    if (tid < 64) {
        float a = b2[tid];
        for (int h = 0; h < 64; ++h) a = fmaf(hbar[h], W2[h * 64 + tid], a);
        t[tid] = a;
    }
    __syncthreads();
    float a = bf[tid];
    for (int h = 0; h < 64; ++h) a = fmaf(t[h], Wf[h * 128 + tid], a);
    out[g * 128 + tid] = a;
}

// ---------------------------------------------------------------------------
extern "C" void kernel_launch(void* const* d_in, const int* in_sizes, int n_in,
                              void* d_out, int out_size, void* d_ws, size_t ws_size,
                              hipStream_t stream)
{
    const float* x  = (const float*)d_in[0];
    const float* W1 = (const float*)d_in[2];
    const float* b1 = (const float*)d_in[3];
    const float* W2 = (const float*)d_in[4];
    const float* b2 = (const float*)d_in[5];
    const float* Wf = (const float*)d_in[6];
    const float* bf = (const float*)d_in[7];
    float* out = (float*)d_out;

    char* ws = (char*)d_ws;
    const size_t N  = (size_t)G_ * NP_;                 // 131072
    const size_t MB = 1024 * 1024;
    float*    v    = (float*)ws;                        //  0 .. 32MB
    int*      idxw = (int*)(ws + 32 * MB);              // 32 .. 40MB
    float*    P    = (float*)(ws + 40 * MB);            // 40 .. 41MB
    uint16_t* zh   = (uint16_t*)(ws + 41 * MB);         // 41 .. 45MB
    uint16_t* zl   = (uint16_t*)(ws + 45 * MB);         // 45 .. 49MB
    float*    sqp  = (float*)(ws + 49 * MB);            // 49 .. 49.5MB

    prep_kernel  <<<(int)(N / 256), 256, 0, stream>>>(x, zh, zl, sqp);
    knn_kernel   <<<G_ * 8, 512, 0, stream>>>(x, zh, zl, sqp, idxw);
    v_kernel     <<<2048, 256, 0, stream>>>(x, W1, v);
    gather_kernel<<<G_ * 8, 256, 0, stream>>>(x, W1, b1, v, idxw, P);
    head_kernel  <<<G_, 128, 0, stream>>>(P, W2, b2, Wf, bf, out);
}